// Round 5
// baseline (1700.015 us; speedup 1.0000x reference)
//
#include <hip/hip_runtime.h>
#include <math.h>

// ---------------- problem constants ----------------
#define NLAY 120         // LSTM layers
#define TT   1016        // LSTM time steps (1024 - 4 - 4)
#define NB   64          // batches of 16 steps
#define RB   8           // L3 ring depth in batches (power of 2)
#define IRS  32          // intra-block inter-wave LDS ring slots (power of 2)
#define WPB  10          // waves per block (stages)
#define LPW  4           // layers per wave (16-lane DPP rows)
#define TPB2 640         // 10 waves x 64 lanes
#define BIGF (1 << 20)

typedef float v2f __attribute__((ext_vector_type(2)));
typedef float v4f __attribute__((ext_vector_type(4)));

__device__ __forceinline__ float fast_rcp(float x) { return __builtin_amdgcn_rcpf(x); }
__device__ __forceinline__ float fast_sig(float x) { return fast_rcp(1.f + __expf(-x)); }
__device__ __forceinline__ float fast_tanh(float x) { return 1.f - 2.f * fast_rcp(1.f + __expf(2.f * x)); }

// DPP row rotate-right: dst lane i <- src lane (i-R)&15 within each 16-lane row.
// (Direction verified vs rocPRIM scan idiom: row_shr:1 = lane i reads lane i-1; ror wraps.)
template<int R>
__device__ __forceinline__ float rotr(float x) {
  return __int_as_float(__builtin_amdgcn_update_dpp(
      0, __float_as_int(x), 0x120 + R, 0xf, 0xf, true));
}

// agent-scope relaxed poll (global flags); s_sleep on miss; watchdog fails loud, never hangs
__device__ __forceinline__ int poll_ge_ag(const int* p, int tgt, int cur) {
  long g = 0;
  while (cur < tgt) {
    cur = __hip_atomic_load(p, __ATOMIC_RELAXED, __HIP_MEMORY_SCOPE_AGENT);
    if (cur >= tgt) break;
    __builtin_amdgcn_s_sleep(1);
    if (++g > 400000L) break;
  }
  return cur;
}
// workgroup-scope relaxed poll on an LDS flag (ds_read spin)
__device__ __forceinline__ int poll_ge_wg(const int* p, int tgt, int cur) {
  long g = 0;
  while (cur < tgt) {
    cur = __hip_atomic_load(p, __ATOMIC_RELAXED, __HIP_MEMORY_SCOPE_WORKGROUP);
    if (cur >= tgt) break;
    __builtin_amdgcn_s_sleep(1);
    if (++g > 400000L) break;
  }
  return cur;
}

// ---------------- conv1d(6->6,K=5,valid) + bias, accumulate BN stats ----------------
__global__ void k_conv(const float* __restrict__ xin, const float* __restrict__ cw,
                       const float* __restrict__ cb, const float* __restrict__ aff,
                       float* __restrict__ yout, float* __restrict__ stat,
                       int Tin, int Tout, int use_aff)
{
  const int bx = blockIdx.x;            // 0..383 : b*6+co
  const int b = bx / 6, co = bx - b * 6;
  const int tid = threadIdx.x;          // 256
  __shared__ float wsh[30];
  __shared__ float ssh[6], shsh[6];
  if (tid < 30) wsh[tid] = cw[co * 30 + tid];
  if (tid < 6) {
    ssh[tid]  = use_aff ? aff[tid] : 1.f;
    shsh[tid] = use_aff ? aff[6 + tid] : 0.f;
  }
  __syncthreads();
  const float bias = cb[co];
  float lsum = 0.f, lsq = 0.f;
  for (int t = tid; t < Tout; t += 256) {
    float acc = bias;
#pragma unroll
    for (int ci = 0; ci < 6; ++ci) {
      const float* xr = xin + ((size_t)b * 6 + ci) * Tin + t;
      const float s = ssh[ci], sh = shsh[ci];
#pragma unroll
      for (int k = 0; k < 5; ++k) {
        float v = xr[k];
        if (use_aff) v = fmaxf(fmaf(s, v, sh), 0.f);
        acc += wsh[ci * 5 + k] * v;
      }
    }
    yout[((size_t)b * 6 + co) * Tout + t] = acc;
    lsum += acc; lsq += acc * acc;
  }
  __shared__ float rs[256], rq[256];
  rs[tid] = lsum; rq[tid] = lsq;
  __syncthreads();
  for (int s = 128; s > 0; s >>= 1) {
    if (tid < s) { rs[tid] += rs[tid + s]; rq[tid] += rq[tid + s]; }
    __syncthreads();
  }
  if (tid == 0) { atomicAdd(&stat[co], rs[0]); atomicAdd(&stat[6 + co], rq[0]); }
}

// ---------------- finalize BN: stats -> per-channel scale/shift ----------------
__global__ void k_finalize(const float* __restrict__ stat,
                           const float* __restrict__ gamma, const float* __restrict__ beta,
                           float* __restrict__ aff, float invN)
{
  const int c = threadIdx.x;
  if (c < 6) {
    float mean = stat[c] * invN;
    float var  = stat[6 + c] * invN - mean * mean;
    float sc   = gamma[c] * rsqrtf(var + 1e-5f);
    aff[c]     = sc;
    aff[6 + c] = fmaf(-mean, sc, beta[c]);
  }
}

// ---------------- BN2+ReLU + attn projection (6->12) + ReLU; write seq0[t][b*12+j] ----------------
__global__ void k_attn(const float* __restrict__ y2, const float* __restrict__ aff2,
                       const float* __restrict__ aw, const float* __restrict__ ab,
                       float* __restrict__ seq0)
{
  const int t = blockIdx.x;             // 0..1015
  const int tid = threadIdx.x;          // 0..767
  __shared__ float zb[6 * 64];
  if (tid < 384) {
    const int c = tid >> 6, bb = tid & 63;
    float v = y2[((size_t)bb * 6 + c) * TT + t];
    zb[c * 64 + bb] = fmaxf(fmaf(aff2[c], v, aff2[6 + c]), 0.f);
  }
  __syncthreads();
  const int b = tid / 12, j = tid - b * 12;
  float acc = ab[j];
#pragma unroll
  for (int c = 0; c < 6; ++c) acc += aw[j * 6 + c] * zb[c * 64 + b];
  seq0[(size_t)t * 768 + tid] = fmaxf(acc, 0.f);
}

// ---------------- 120-layer LSTM: DPP register recurrence, free-running waves ----------------
// grid = 192 blocks: bid = chain*3 + seg (3 segs x 40 layers). Wave w = 4-layer stage;
// ROW r = 16 lanes (12 active) = one layer; p = lane>>4 (0..3), j = lane&15.
// Diagonal: at step s, row p computes t = s - p.
// Own-group h(t-1) all-gather = 15 v_mov_dpp row_ror ops (VALU, ~4cyc) instead of the
// ds_write->ds_read round trip (~200cyc, zero slack). row_ror:R: lane j receives
// h[(j-R)&15], so weight slot r holds wh[j][(j-r)&15] (FIX of round-4's (j+r) inversion).
// x-side (prev row's h, ONE step of slack from the diagonal) stays via hloc LDS double
// buffer: 1 write + 3 b128 reads per step. Wave->wave: iring + RELAXED LDS flags.
// Block->block: 16-step batches via L3 ring; tailer prog post RELEASE.
__global__ __launch_bounds__(TPB2, 3) void k_lstm(
    const float* __restrict__ wih, const float* __restrict__ whh,
    const float* __restrict__ bih, const float* __restrict__ bhh,
    const float* __restrict__ seq0, float* __restrict__ ring,
    int* __restrict__ prog, int* __restrict__ cons,
    float* __restrict__ hfin)
{
  const int bid  = blockIdx.x;         // 0..191
  const int c    = bid / 3;            // chain = batch element
  const int seg  = bid - c * 3;        // 0..2
  const int tid  = threadIdx.x;
  const int w    = tid >> 6;           // wave 0..9
  const int lane = tid & 63;
  const int p    = lane >> 4;          // row 0..3 (= layer within wave)
  const int j    = lane & 15;          // 0..15; active if j<12
  const bool actj = (j < 12);
  const int l    = seg * 40 + w * 4 + p;

  // ---- LDS ----
  __shared__ __align__(16) float hloc[WPB][2][64];      // [wave][buf][row*16+j] : row->row+1 x feed
  __shared__ __align__(16) float iring[WPB - 1][IRS][12]; // wave w -> w+1
  __shared__ __align__(16) float xring[2][16][12];      // feeder input (wave 0 private)
  __shared__ __align__(16) float oring[16][12];         // tailer staging (wave 9 private)
  __shared__ int pflag[WPB];                            // produced-count, posted by wave w (w<9)
  __shared__ int cflag[WPB + 1];                        // consumed-count, posted by wave w (w>0)
  float* xrf = &xring[0][0][0];

  if (tid < WPB) pflag[tid] = 0;
  if (tid < WPB + 1) cflag[tid] = 0;
  hloc[w][0][lane] = 0.f; hloc[w][1][lane] = 0.f;
  __syncthreads();   // ONE barrier, before the main loop only

  // ---- weights ----
  // x-side: 12-k, gate pairs (i,f),(g,o) -> v_pk_fma with op_sel splats
  v2f wx_if[12], wx_go[12];
  // h-side: 16-r rotated: slot r pairs with rotr<r>(hn) = h[(j-r)&15]; zero if pad k
  v2f whr_if[16], whr_go[16];
  v2f b_if = (v2f){0.f, 0.f}, b_go = (v2f){0.f, 0.f};
  {
    const float* wi = wih + l * 576;
    const float* wh = whh + l * 576;
#pragma unroll
    for (int k = 0; k < 12; ++k) {
      if (actj) {
        wx_if[k] = (v2f){ wi[(j     ) * 12 + k], wi[(j + 12) * 12 + k] };
        wx_go[k] = (v2f){ wi[(j + 24) * 12 + k], wi[(j + 36) * 12 + k] };
      } else {
        wx_if[k] = (v2f){0.f, 0.f}; wx_go[k] = (v2f){0.f, 0.f};
      }
    }
#pragma unroll
    for (int r = 0; r < 16; ++r) {
      const int kk = (j - r) & 15;       // row_ror:r delivers h[(j-r)&15]
      if (actj && kk < 12) {
        whr_if[r] = (v2f){ wh[(j     ) * 12 + kk], wh[(j + 12) * 12 + kk] };
        whr_go[r] = (v2f){ wh[(j + 24) * 12 + kk], wh[(j + 36) * 12 + kk] };
      } else {
        whr_if[r] = (v2f){0.f, 0.f}; whr_go[r] = (v2f){0.f, 0.f};
      }
    }
    if (actj) {
      const float* ba = bih + l * 48;
      const float* bb = bhh + l * 48;
      b_if = (v2f){ ba[j]      + bb[j],      ba[j + 12] + bb[j + 12] };
      b_go = (v2f){ ba[j + 24] + bb[j + 24], ba[j + 36] + bb[j + 36] };
    }
  }

  // ---- feeder / tailer plumbing (2 hops per chain) ----
  const int hop_in  = c * 2 + seg - 1;                 // valid if seg>0
  const int hop_out = c * 2 + seg;                     // valid if seg<2
  const float* rin  = ring + (size_t)((seg > 0) ? hop_in : 0) * (RB * 192);
  float*       rout = ring + (size_t)((seg < 2) ? hop_out : 0) * (RB * 192);
  const bool is_feeder = (w == 0);
  const bool is_tailer = (w == WPB - 1) && (seg < 2);

  const int f0 = lane, f1 = lane + 64, f2 = lane + 128;   // cooperative 192-float copy
  const int s0o0 = (f0 / 12) * 768 + (f0 % 12);           // seq0 gather offsets
  const int s0o1 = (f1 / 12) * 768 + (f1 % 12);
  const int s0o2 = (f2 / 12) * 768 + (f2 % 12);

  auto ld_batch = [&](int m, float* d) {
    if (seg == 0) {
      const float* b = seq0 + (size_t)m * 16 * 768 + c * 12;
      d[0] = b[s0o0]; d[1] = b[s0o1]; d[2] = b[s0o2];
    } else {
      const float* b = rin + (m & (RB - 1)) * 192;
      d[0] = __hip_atomic_load(b + f0, __ATOMIC_RELAXED, __HIP_MEMORY_SCOPE_AGENT);
      d[1] = __hip_atomic_load(b + f1, __ATOMIC_RELAXED, __HIP_MEMORY_SCOPE_AGENT);
      d[2] = __hip_atomic_load(b + f2, __ATOMIC_RELAXED, __HIP_MEMORY_SCOPE_AGENT);
    }
  };

  float pend[3] = {0.f, 0.f, 0.f};
  int kp = 0, kcons = 0;
  if (is_feeder) {
    if (seg > 0) kp = poll_ge_ag(&prog[hop_in], 2, 0);
    float cur[3];
    ld_batch(0, cur);
    ld_batch(1, pend);
    xrf[f0] = cur[0]; xrf[f1] = cur[1]; xrf[f2] = cur[2];   // batch 0 -> buffer 0
  }

  float hn = 0.f, cst = 0.f;       // own h(t-1), c(t-1) in registers
  int pcache = 0, ccache = 0;

  // ---- one LSTM step; `guard` constant-folds per call site ----
  auto step = [&](int s, bool guard) __attribute__((always_inline)) {
    const int t  = s - p;
    const int rb = (s & 1) ^ 1, wb = s & 1;

    // x source: prev row's h (1 step slack) or feeder/iring for row 0
    const float* ax;
    if (p == 0) ax = (w == 0) ? (xrf + ((s >> 4) & 1) * 192 + (s & 15) * 12)
                              : (&iring[w - 1][s & (IRS - 1)][0]);
    else        ax = &hloc[w][rb][(p - 1) * 16];
    v4f xA = ((const v4f*)ax)[0], xB = ((const v4f*)ax)[1], xC = ((const v4f*)ax)[2];
    float xv[12] = {xA.x,xA.y,xA.z,xA.w, xB.x,xB.y,xB.z,xB.w, xC.x,xC.y,xC.z,xC.w};

    // own-row h all-gather: 15 DPP rotates (VALU), hv[r] = h[(j-r)&15]
    float hv[16];
    hv[0]  = hn;
    hv[1]  = rotr<1>(hn);  hv[2]  = rotr<2>(hn);  hv[3]  = rotr<3>(hn);
    hv[4]  = rotr<4>(hn);  hv[5]  = rotr<5>(hn);  hv[6]  = rotr<6>(hn);
    hv[7]  = rotr<7>(hn);  hv[8]  = rotr<8>(hn);  hv[9]  = rotr<9>(hn);
    hv[10] = rotr<10>(hn); hv[11] = rotr<11>(hn); hv[12] = rotr<12>(hn);
    hv[13] = rotr<13>(hn); hv[14] = rotr<14>(hn); hv[15] = rotr<15>(hn);

    // h-side: two 8-deep chains per gate-pair; x-side: one 12-deep chain per gate-pair
    v2f hia = b_if, hib = (v2f){0.f, 0.f};
    v2f hga = b_go, hgb = (v2f){0.f, 0.f};
#pragma unroll
    for (int r = 0; r < 8; ++r) {
      v2f ha = { hv[r], hv[r] }, hb = { hv[r + 8], hv[r + 8] };
      hia = __builtin_elementwise_fma(whr_if[r],     ha, hia);
      hga = __builtin_elementwise_fma(whr_go[r],     ha, hga);
      hib = __builtin_elementwise_fma(whr_if[r + 8], hb, hib);
      hgb = __builtin_elementwise_fma(whr_go[r + 8], hb, hgb);
    }
    v2f xif = (v2f){0.f, 0.f}, xgo = (v2f){0.f, 0.f};
#pragma unroll
    for (int k = 0; k < 12; ++k) {
      v2f xx = { xv[k], xv[k] };
      xif = __builtin_elementwise_fma(wx_if[k], xx, xif);
      xgo = __builtin_elementwise_fma(wx_go[k], xx, xgo);
    }
    v2f aif = (hia + hib) + xif;
    v2f ago = (hga + hgb) + xgo;
    float ig = fast_sig(aif.x), fg = fast_sig(aif.y);
    float gg = fast_tanh(ago.x), og = fast_sig(ago.y);

    if (!guard) {
      cst = fg * cst + ig * gg;
      float h2 = og * fast_tanh(cst);
      hn = actj ? h2 : 0.f;                     // pad lanes stay 0 (rot sources)
      hloc[w][wb][p * 16 + j] = hn;             // feed row p+1 (1 step slack)
      if (p == 3 && actj) {
        if (w < WPB - 1) iring[w][t & (IRS - 1)][j] = hn;
        else if (seg < 2) oring[t & 15][j] = hn;
      }
    } else {
      const bool run = (t >= 0) && (t < TT);    // row-uniform -> DPP-safe
      if (run) {
        cst = fg * cst + ig * gg;
        float h2 = og * fast_tanh(cst);
        hn = actj ? h2 : 0.f;
        hloc[w][wb][p * 16 + j] = hn;
        if (p == 3 && actj) {
          if (w < WPB - 1) iring[w][t & (IRS - 1)][j] = hn;
          else if (seg < 2) oring[t & 15][j] = hn;
        }
        if (t == TT - 1 && actj) hfin[l * 768 + c * 12 + j] = hn;
      }
    }
  };

  for (int s4 = 0; s4 < 1024; s4 += 4) {
    // ---- batch boundary: feeder publishes batch m+1, starts loads for m+2 ----
    if (is_feeder && (s4 & 15) == 0) {
      const int m = s4 >> 4;
      if (m + 1 < NB) {
        float* xd = xrf + ((m + 1) & 1) * 192;
        xd[f0] = pend[0]; xd[f1] = pend[1]; xd[f2] = pend[2];
      }
      if (m + 2 < NB) {
        if (seg > 0 && kp < m + 3) kp = poll_ge_ag(&prog[hop_in], m + 3, kp);
        ld_batch(m + 2, pend);     // stays in flight for the next 16 steps (no drains now)
      }
      if (seg > 0 && lane == 0)
        __hip_atomic_store(&cons[hop_in], m, __ATOMIC_RELAXED, __HIP_MEMORY_SCOPE_AGENT);
    }

    // ---- relaxed LDS flag checks, once per 4 steps ----
    if (w > 0 && s4 < TT) {
      const int tgt = (s4 + 4 < TT) ? (s4 + 4) : TT;
      if (pcache < tgt) {
        pcache = poll_ge_wg(&pflag[w - 1], tgt, pcache);
        asm volatile("" ::: "memory");
      }
    }
    if (w < WPB - 1 && s4 >= 32) {
      const int tgt = s4 - 28;     // skew-3 geometry: consumer must be within 28 steps
      if (ccache < tgt) {
        ccache = poll_ge_wg(&cflag[w + 1], tgt, ccache);
        asm volatile("" ::: "memory");
      }
    }

    if (s4 >= 4 && s4 < 1012) {
      step(s4 + 0, false); step(s4 + 1, false); step(s4 + 2, false); step(s4 + 3, false);
    } else {
      step(s4 + 0, true);  step(s4 + 1, true);  step(s4 + 2, true);  step(s4 + 3, true);
    }

    // ---- tailer: flush a completed 16-step batch to the L3 ring ----
    if (is_tailer) {
      if ((((s4 & 15) == 0) && s4 >= 16) || s4 == 1016) {
        const int m4 = (s4 - 1) >> 4;
        if (kcons < m4 - (RB - 1) + 1)
          kcons = poll_ge_ag(&cons[hop_out], m4 - RB + 1, kcons);
        const float* orf = &oring[0][0];
        float o0 = orf[f0], o1 = orf[f1], o2 = orf[f2];
        float* d = rout + (m4 & (RB - 1)) * 192;
        __hip_atomic_store(d + f0, o0, __ATOMIC_RELAXED, __HIP_MEMORY_SCOPE_AGENT);
        __hip_atomic_store(d + f1, o1, __ATOMIC_RELAXED, __HIP_MEMORY_SCOPE_AGENT);
        __hip_atomic_store(d + f2, o2, __ATOMIC_RELAXED, __HIP_MEMORY_SCOPE_AGENT);
        if (lane == 0)   // RELEASE: drains this wave's 3 stores; other waves keep running
          __hip_atomic_store(&prog[hop_out], m4 + 1, __ATOMIC_RELEASE, __HIP_MEMORY_SCOPE_AGENT);
      }
    }

    // ---- relaxed flag posts (DS pipe in-order per wave orders data before flag) ----
    if (lane == 0) {
      asm volatile("" ::: "memory");
      if (w < WPB - 1)
        __hip_atomic_store(&pflag[w], s4, __ATOMIC_RELAXED, __HIP_MEMORY_SCOPE_WORKGROUP);
      if (w > 0 && s4 + 3 < TT)
        __hip_atomic_store(&cflag[w], s4 + 4, __ATOMIC_RELAXED, __HIP_MEMORY_SCOPE_WORKGROUP);
    }
  }

  // ---- epilogue: unblock any remaining pollers ----
  if (lane == 0) {
    asm volatile("" ::: "memory");
    if (w < WPB - 1) __hip_atomic_store(&pflag[w], BIGF, __ATOMIC_RELAXED, __HIP_MEMORY_SCOPE_WORKGROUP);
    if (w > 0) __hip_atomic_store(&cflag[w], BIGF, __ATOMIC_RELAXED, __HIP_MEMORY_SCOPE_WORKGROUP);
    if (is_feeder && seg > 0)
      __hip_atomic_store(&cons[hop_in], BIGF, __ATOMIC_RELAXED, __HIP_MEMORY_SCOPE_AGENT);
  }
}

// ---------------- head: lin1+relu, lin2+relu, mu, softplus(sigma) ----------------
__global__ void k_head(const float* __restrict__ hfin,
                       const float* __restrict__ w1, const float* __restrict__ b1,
                       const float* __restrict__ w2, const float* __restrict__ b2,
                       const float* __restrict__ wm, const float* __restrict__ bm,
                       const float* __restrict__ wsg, const float* __restrict__ bsg,
                       float* __restrict__ out)
{
  const int tid = threadIdx.x;
  __shared__ float s1[144], s2[144], sm[144], ss[144];
  __shared__ float v1[12], v2[12], vm[12], vs[12];
  if (tid < 144) { s1[tid] = w1[tid]; s2[tid] = w2[tid]; sm[tid] = wm[tid]; ss[tid] = wsg[tid]; }
  if (tid < 12)  { v1[tid] = b1[tid]; v2[tid] = b2[tid]; vm[tid] = bm[tid]; vs[tid] = bsg[tid]; }
  __syncthreads();
  const int r = blockIdx.x * 256 + tid;   // 0..7679 = b*120 + l
  const int b = r / 120, l = r - b * 120;
  float h[12];
#pragma unroll
  for (int k = 0; k < 12; ++k) h[k] = hfin[l * 768 + b * 12 + k];
  float u1[12];
#pragma unroll
  for (int u = 0; u < 12; ++u) {
    float a = v1[u];
#pragma unroll
    for (int k = 0; k < 12; ++k) a += s1[u * 12 + k] * h[k];
    u1[u] = fmaxf(a, 0.f);
  }
  float u2[12];
#pragma unroll
  for (int u = 0; u < 12; ++u) {
    float a = v2[u];
#pragma unroll
    for (int k = 0; k < 12; ++k) a += s2[u * 12 + k] * u1[k];
    u2[u] = fmaxf(a, 0.f);
  }
  const size_t base = (size_t)r * 12;
#pragma unroll
  for (int u = 0; u < 12; ++u) out[base + u] = u2[u];
#pragma unroll
  for (int u = 0; u < 12; ++u) {
    float a = vm[u];
#pragma unroll
    for (int k = 0; k < 12; ++k) a += sm[u * 12 + k] * u2[k];
    out[92160 + base + u] = a;
  }
#pragma unroll
  for (int u = 0; u < 12; ++u) {
    float a = vs[u];
#pragma unroll
    for (int k = 0; k < 12; ++k) a += ss[u * 12 + k] * u2[k];
    out[184320 + base + u] = fmaxf(a, 0.f) + log1pf(expf(-fabsf(a)));
  }
}

// ---------------- launcher ----------------
extern "C" void kernel_launch(void* const* d_in, const int* in_sizes, int n_in,
                              void* d_out, int out_size, void* d_ws, size_t ws_size,
                              hipStream_t stream)
{
  const float* x   = (const float*)d_in[0];
  const float* c1w = (const float*)d_in[1];
  const float* c1b = (const float*)d_in[2];
  const float* g1  = (const float*)d_in[3];
  const float* be1 = (const float*)d_in[4];
  const float* c2w = (const float*)d_in[5];
  const float* c2b = (const float*)d_in[6];
  const float* g2  = (const float*)d_in[7];
  const float* be2 = (const float*)d_in[8];
  const float* aw  = (const float*)d_in[9];
  const float* ab  = (const float*)d_in[10];
  const float* wih = (const float*)d_in[11];
  const float* whh = (const float*)d_in[12];
  const float* bih = (const float*)d_in[13];
  const float* bhh = (const float*)d_in[14];
  const float* l1w = (const float*)d_in[15];
  const float* l1b = (const float*)d_in[16];
  const float* l2w = (const float*)d_in[17];
  const float* l2b = (const float*)d_in[18];
  const float* muw = (const float*)d_in[19];
  const float* mub = (const float*)d_in[20];
  const float* sgw = (const float*)d_in[21];
  const float* sgb = (const float*)d_in[22];

  float* ws    = (float*)d_ws;
  float* stat1 = ws;                    // 12
  float* stat2 = ws + 12;               // 12
  float* aff1  = ws + 24;               // 12
  float* aff2  = ws + 36;               // 12
  int*   prog  = (int*)(ws + 64);       // 128 used
  int*   cons  = (int*)(ws + 304);      // 128 used
  float* y1    = ws + 576;              // 64*6*1020
  float* y2    = y1 + 391680;           // 64*6*1016
  float* seq0  = y2 + 390144;           // 1016*768
  float* ring  = seq0 + 780288;         // 128 hops * 8 batches * 192 floats
  float* hfin  = ring + (size_t)128 * RB * 192;   // 120*768

  hipMemsetAsync(d_ws, 0, 576 * sizeof(float), stream);  // zero stats + flags

  k_conv<<<384, 256, 0, stream>>>(x, c1w, c1b, nullptr, y1, stat1, 1024, 1020, 0);
  k_finalize<<<1, 64, 0, stream>>>(stat1, g1, be1, aff1, 1.f / 65280.f);
  k_conv<<<384, 256, 0, stream>>>(y1, c2w, c2b, aff1, y2, stat2, 1020, 1016, 1);
  k_finalize<<<1, 64, 0, stream>>>(stat2, g2, be2, aff2, 1.f / 65024.f);
  k_attn<<<1016, 768, 0, stream>>>(y2, aff2, aw, ab, seq0);
  k_lstm<<<192, TPB2, 0, stream>>>(wih, whh, bih, bhh, seq0, ring, prog, cons, hfin);
  k_head<<<30, 256, 0, stream>>>(hfin, l1w, l1b, l2w, l2b, muw, mub, sgw, sgb, (float*)d_out);
}

// Round 6
// 819.291 us; speedup vs baseline: 2.0750x; 2.0750x over previous
//
#include <hip/hip_runtime.h>
#include <math.h>

// ---------------- problem constants ----------------
#define NLAY 120         // LSTM layers
#define TT   1016        // LSTM time steps (1024 - 4 - 4)
#define NB   64          // batches of 16 steps (64*16 = 1024 >= TT+4)
#define RB   8           // L3 ring depth in batches (power of 2)
#define IRS  32          // intra-block inter-wave LDS ring slots (power of 2)
#define TPB  384         // 6 waves x 64 lanes; wave = 5 layers x 12 hidden (lanes 60-63 idle)
#define BIGF (1 << 20)

typedef float v2f __attribute__((ext_vector_type(2)));

__device__ __forceinline__ float fast_rcp(float x) { return __builtin_amdgcn_rcpf(x); }
__device__ __forceinline__ float fast_sig(float x) { return fast_rcp(1.f + __expf(-x)); }
__device__ __forceinline__ float fast_tanh(float x) { return 1.f - 2.f * fast_rcp(1.f + __expf(2.f * x)); }

// agent-scope relaxed poll (global flags); s_sleep on miss; watchdog fails loud, never hangs
__device__ __forceinline__ int poll_ge_ag(const int* p, int tgt, int cur) {
  long g = 0;
  while (cur < tgt) {
    cur = __hip_atomic_load(p, __ATOMIC_RELAXED, __HIP_MEMORY_SCOPE_AGENT);
    if (cur >= tgt) break;
    __builtin_amdgcn_s_sleep(1);
    if (++g > 400000L) break;
  }
  return cur;
}
// workgroup-scope relaxed poll on an LDS flag (ds_read spin)
__device__ __forceinline__ int poll_ge_wg(const int* p, int tgt, int cur) {
  long g = 0;
  while (cur < tgt) {
    cur = __hip_atomic_load(p, __ATOMIC_RELAXED, __HIP_MEMORY_SCOPE_WORKGROUP);
    if (cur >= tgt) break;
    __builtin_amdgcn_s_sleep(1);
    if (++g > 400000L) break;
  }
  return cur;
}

// ---------------- conv1d(6->6,K=5,valid) + bias, accumulate BN stats ----------------
__global__ void k_conv(const float* __restrict__ xin, const float* __restrict__ cw,
                       const float* __restrict__ cb, const float* __restrict__ aff,
                       float* __restrict__ yout, float* __restrict__ stat,
                       int Tin, int Tout, int use_aff)
{
  const int bx = blockIdx.x;            // 0..383 : b*6+co
  const int b = bx / 6, co = bx - b * 6;
  const int tid = threadIdx.x;          // 256
  __shared__ float wsh[30];
  __shared__ float ssh[6], shsh[6];
  if (tid < 30) wsh[tid] = cw[co * 30 + tid];
  if (tid < 6) {
    ssh[tid]  = use_aff ? aff[tid] : 1.f;
    shsh[tid] = use_aff ? aff[6 + tid] : 0.f;
  }
  __syncthreads();
  const float bias = cb[co];
  float lsum = 0.f, lsq = 0.f;
  for (int t = tid; t < Tout; t += 256) {
    float acc = bias;
#pragma unroll
    for (int ci = 0; ci < 6; ++ci) {
      const float* xr = xin + ((size_t)b * 6 + ci) * Tin + t;
      const float s = ssh[ci], sh = shsh[ci];
#pragma unroll
      for (int k = 0; k < 5; ++k) {
        float v = xr[k];
        if (use_aff) v = fmaxf(fmaf(s, v, sh), 0.f);
        acc += wsh[ci * 5 + k] * v;
      }
    }
    yout[((size_t)b * 6 + co) * Tout + t] = acc;
    lsum += acc; lsq += acc * acc;
  }
  __shared__ float rs[256], rq[256];
  rs[tid] = lsum; rq[tid] = lsq;
  __syncthreads();
  for (int s = 128; s > 0; s >>= 1) {
    if (tid < s) { rs[tid] += rs[tid + s]; rq[tid] += rq[tid + s]; }
    __syncthreads();
  }
  if (tid == 0) { atomicAdd(&stat[co], rs[0]); atomicAdd(&stat[6 + co], rq[0]); }
}

// ---------------- finalize BN: stats -> per-channel scale/shift ----------------
__global__ void k_finalize(const float* __restrict__ stat,
                           const float* __restrict__ gamma, const float* __restrict__ beta,
                           float* __restrict__ aff, float invN)
{
  const int c = threadIdx.x;
  if (c < 6) {
    float mean = stat[c] * invN;
    float var  = stat[6 + c] * invN - mean * mean;
    float sc   = gamma[c] * rsqrtf(var + 1e-5f);
    aff[c]     = sc;
    aff[6 + c] = fmaf(-mean, sc, beta[c]);
  }
}

// ---------------- BN2+ReLU + attn projection (6->12) + ReLU; write seq0[t][b*12+j] ----------------
__global__ void k_attn(const float* __restrict__ y2, const float* __restrict__ aff2,
                       const float* __restrict__ aw, const float* __restrict__ ab,
                       float* __restrict__ seq0)
{
  const int t = blockIdx.x;             // 0..1015
  const int tid = threadIdx.x;          // 0..767
  __shared__ float zb[6 * 64];
  if (tid < 384) {
    const int c = tid >> 6, bb = tid & 63;
    float v = y2[((size_t)bb * 6 + c) * TT + t];
    zb[c * 64 + bb] = fmaxf(fmaf(aff2[c], v, aff2[6 + c]), 0.f);
  }
  __syncthreads();
  const int b = tid / 12, j = tid - b * 12;
  float acc = ab[j];
#pragma unroll
  for (int c = 0; c < 6; ++c) acc += aw[j * 6 + c] * zb[c * 64 + b];
  seq0[(size_t)t * 768 + tid] = fmaxf(acc, 0.f);
}

// ---------------- 120-layer LSTM: free-running waves, relaxed LDS flag protocol ----------------
// grid = 256 blocks: bid = chain*4 + seg. Wave w = 5-layer stage; lane (p,j) = layer w*5+p.
// Diagonal: at step s, group p computes t = s - p.
// ROUND-6 CHANGE (single variable vs the 721us r0 kernel): weights/biases are PINNED into
// VGPRs via empty asm "+v" defs after loading. Without this, LLVM promotes the kernarg
// weight pointers to constant addrspace and SINKS the loads into the hot loop (observable:
// VGPR_Count=92 < the 96 weight values alone) — every step re-streams ~150KB/CU of weights
// through L1/L2, which is what paced all previous rounds. The asm def is not
// rematerializable, forcing true register residency (budget: ~160 < 256 cap at 2 blocks/CU).
__global__ __launch_bounds__(TPB, 2) void k_lstm(
    const float* __restrict__ wih, const float* __restrict__ whh,
    const float* __restrict__ bih, const float* __restrict__ bhh,
    const float* __restrict__ seq0, float* __restrict__ ring,
    int* __restrict__ prog, int* __restrict__ cons,
    float* __restrict__ hfin)
{
  const int bid  = blockIdx.x;         // 0..255
  const int c    = bid >> 2;           // chain = batch element
  const int seg  = bid & 3;
  const int tid  = threadIdx.x;
  const int w    = tid >> 6;           // wave 0..5
  const int lane = tid & 63;
  const int p    = lane / 12;          // 0..5 (5 = pad group)
  const int j    = lane - p * 12;
  const bool act = (p < 5);
  const int pc   = act ? p : 0;        // clamped for safe addressing
  const int l    = seg * 30 + w * 5 + pc;

  // ---- LDS ----
  __shared__ __align__(16) float hloc[6][2][64];        // per-wave double buffer (+pad slots 60..63)
  __shared__ __align__(16) float iring[5][IRS][12];     // wave w -> w+1
  __shared__ __align__(16) float xring[2][16][12];      // feeder input (wave 0 private)
  __shared__ __align__(16) float oring[16][12];         // tailer staging (wave 5 private)
  __shared__ int pflag[6];                              // produced-count, posted by wave w (w<5)
  __shared__ int cflag[8];                              // consumed-count, posted by wave w (w>0)
  float* xrf = &xring[0][0][0];

  if (tid < 6) pflag[tid] = 0;
  if (tid < 8) cflag[tid] = 0;
  hloc[w][0][lane] = 0.f; hloc[w][1][lane] = 0.f;
  __syncthreads();   // ONE barrier, before the main loop only

  // ---- gate weights as (i,f),(g,o) float2 pairs -> v_pk_fma_f32 ----
  v2f wx_if[12] = {}, wx_go[12] = {}, wh_if[12] = {}, wh_go[12] = {};
  v2f b_if = (v2f){0.f, 0.f}, b_go = (v2f){0.f, 0.f};
  if (act) {
    const float* wi = wih + l * 576;
    const float* wh = whh + l * 576;
#pragma unroll
    for (int k = 0; k < 12; ++k) {
      wx_if[k] = (v2f){ wi[(j     ) * 12 + k], wi[(j + 12) * 12 + k] };
      wx_go[k] = (v2f){ wi[(j + 24) * 12 + k], wi[(j + 36) * 12 + k] };
      wh_if[k] = (v2f){ wh[(j     ) * 12 + k], wh[(j + 12) * 12 + k] };
      wh_go[k] = (v2f){ wh[(j + 24) * 12 + k], wh[(j + 36) * 12 + k] };
    }
    const float* ba = bih + l * 48;
    const float* bb = bhh + l * 48;
    b_if = (v2f){ ba[j]      + bb[j],      ba[j + 12] + bb[j + 12] };
    b_go = (v2f){ ba[j + 24] + bb[j + 24], ba[j + 36] + bb[j + 36] };
  }
  // PIN: asm def breaks load-rematerialization; weights become true VGPR residents.
#pragma unroll
  for (int k = 0; k < 12; ++k) {
    asm volatile("" : "+v"(wx_if[k]), "+v"(wx_go[k]));
    asm volatile("" : "+v"(wh_if[k]), "+v"(wh_go[k]));
  }
  asm volatile("" : "+v"(b_if), "+v"(b_go));

  // ---- feeder / tailer plumbing ----
  const int hop_in  = c * 3 + seg - 1;                 // valid if seg>0
  const int hop_out = c * 3 + seg;                     // valid if seg<3
  const float* rin  = ring + (size_t)((seg > 0) ? hop_in : 0) * (RB * 192);
  float*       rout = ring + (size_t)((seg < 3) ? hop_out : 0) * (RB * 192);
  const bool is_feeder = (w == 0);
  const bool is_tailer = (w == 5) && (seg < 3);

  const int f0 = lane, f1 = lane + 64, f2 = lane + 128;   // cooperative 192-float copy
  const int s0o0 = (f0 / 12) * 768 + (f0 % 12);           // seq0 gather offsets
  const int s0o1 = (f1 / 12) * 768 + (f1 % 12);
  const int s0o2 = (f2 / 12) * 768 + (f2 % 12);

  auto ld_batch = [&](int m, float* d) {
    if (seg == 0) {
      const float* b = seq0 + (size_t)m * 16 * 768 + c * 12;
      d[0] = b[s0o0]; d[1] = b[s0o1]; d[2] = b[s0o2];
    } else {
      const float* b = rin + (m & (RB - 1)) * 192;
      d[0] = __hip_atomic_load(b + f0, __ATOMIC_RELAXED, __HIP_MEMORY_SCOPE_AGENT);
      d[1] = __hip_atomic_load(b + f1, __ATOMIC_RELAXED, __HIP_MEMORY_SCOPE_AGENT);
      d[2] = __hip_atomic_load(b + f2, __ATOMIC_RELAXED, __HIP_MEMORY_SCOPE_AGENT);
    }
  };

  float pend[3] = {0.f, 0.f, 0.f};
  int kp = 0, kcons = 0;
  if (is_feeder) {
    if (seg > 0) kp = poll_ge_ag(&prog[hop_in], 2, 0);
    float cur[3];
    ld_batch(0, cur);
    ld_batch(1, pend);
    xrf[f0] = cur[0]; xrf[f1] = cur[1]; xrf[f2] = cur[2];   // batch 0 -> buffer 0
  }

  float cst = 0.f;
  int pcache = 0, ccache = 0;

  // ---- one LSTM step; `guard` constant-folds per call site ----
  auto step = [&](int s, bool guard) __attribute__((always_inline)) {
    const int t  = s - pc;
    const int rb = (s & 1) ^ 1, wb = s & 1;

    const float* ax;
    if (p == 0) ax = (w == 0) ? (xrf + ((s >> 4) & 1) * 192 + (s & 15) * 12)
                              : (&iring[w - 1][s & (IRS - 1)][0]);
    else        ax = &hloc[w][rb][(pc == 0 ? 0 : pc - 1) * 12];
    const float* ah = &hloc[w][rb][pc * 12];

    float4 xA = ((const float4*)ax)[0], xB = ((const float4*)ax)[1], xC = ((const float4*)ax)[2];
    float4 hA = ((const float4*)ah)[0], hB = ((const float4*)ah)[1], hC = ((const float4*)ah)[2];
    float xv[12] = {xA.x,xA.y,xA.z,xA.w, xB.x,xB.y,xB.z,xB.w, xC.x,xC.y,xC.z,xC.w};
    float hv[12] = {hA.x,hA.y,hA.z,hA.w, hB.x,hB.y,hB.z,hB.w, hC.x,hC.y,hC.z,hC.w};

    v2f axif = (v2f){0.f,0.f}, axgo = (v2f){0.f,0.f};
    v2f ahif = b_if, ahgo = b_go;
#pragma unroll
    for (int k = 0; k < 12; ++k) {
      v2f xx = { xv[k], xv[k] };
      axif = __builtin_elementwise_fma(wx_if[k], xx, axif);
      axgo = __builtin_elementwise_fma(wx_go[k], xx, axgo);
    }
#pragma unroll
    for (int k = 0; k < 12; ++k) {
      v2f hh = { hv[k], hv[k] };
      ahif = __builtin_elementwise_fma(wh_if[k], hh, ahif);
      ahgo = __builtin_elementwise_fma(wh_go[k], hh, ahgo);
    }
    v2f aif = axif + ahif, ago = axgo + ahgo;
    float ig = fast_sig(aif.x);
    float fg = fast_sig(aif.y);
    float gg = fast_tanh(ago.x);
    float og = fast_sig(ago.y);

    if (!guard) {
      // steady region: all t valid; idle lanes write their pad slot
      cst = fg * cst + ig * gg;
      float hn = og * fast_tanh(cst);
      hloc[w][wb][p * 12 + j] = hn;
      if (p == 4) {
        if (w < 5) iring[w][t & (IRS - 1)][j] = hn;
        else if (seg < 3) oring[t & 15][j] = hn;
      }
    } else {
      const bool run = act && (t >= 0) && (t < TT);
      if (run) {
        cst = fg * cst + ig * gg;
        float hn = og * fast_tanh(cst);
        hloc[w][wb][p * 12 + j] = hn;
        if (p == 4) {
          if (w < 5) iring[w][t & (IRS - 1)][j] = hn;
          else if (seg < 3) oring[t & 15][j] = hn;
        }
        if (t == TT - 1) hfin[l * 768 + c * 12 + j] = hn;
      }
    }

    // tailer: flush a completed 16-step batch to the L3 ring (wave-uniform branch)
    if (is_tailer) {
      const int t4 = s - 4;
      if (t4 >= 0 && t4 < TT && (((t4 & 15) == 15) || t4 == TT - 1)) {
        const int m4 = t4 >> 4;
        if (kcons < m4 - (RB - 1) + 1)
          kcons = poll_ge_ag(&cons[hop_out], m4 - RB + 1, kcons);
        const float* orf = &oring[0][0];
        float o0 = orf[f0], o1 = orf[f1], o2 = orf[f2];
        float* d = rout + (m4 & (RB - 1)) * 192;
        __hip_atomic_store(d + f0, o0, __ATOMIC_RELAXED, __HIP_MEMORY_SCOPE_AGENT);
        __hip_atomic_store(d + f1, o1, __ATOMIC_RELAXED, __HIP_MEMORY_SCOPE_AGENT);
        __hip_atomic_store(d + f2, o2, __ATOMIC_RELAXED, __HIP_MEMORY_SCOPE_AGENT);
        if (lane == 0)   // RELEASE: drains this wave's 3 stores; other waves keep running
          __hip_atomic_store(&prog[hop_out], m4 + 1, __ATOMIC_RELEASE, __HIP_MEMORY_SCOPE_AGENT);
      }
    }
  };

  for (int s4 = 0; s4 < 1024; s4 += 4) {
    // ---- batch boundary: feeder publishes batch m+1, starts loads for m+2 ----
    if (is_feeder && (s4 & 15) == 0) {
      const int m = s4 >> 4;
      if (m + 1 < NB) {
        float* xd = xrf + ((m + 1) & 1) * 192;
        xd[f0] = pend[0]; xd[f1] = pend[1]; xd[f2] = pend[2];
      }
      if (m + 2 < NB) {
        if (seg > 0 && kp < m + 3) kp = poll_ge_ag(&prog[hop_in], m + 3, kp);
        ld_batch(m + 2, pend);     // stays in flight for the next 16 steps (no drains now)
      }
      if (seg > 0 && lane == 0)
        __hip_atomic_store(&cons[hop_in], m, __ATOMIC_RELAXED, __HIP_MEMORY_SCOPE_AGENT);
    }

    // ---- relaxed LDS flag checks, once per 4 steps ----
    if (w > 0 && s4 < TT) {
      const int tgt = (s4 + 4 < TT) ? (s4 + 4) : TT;
      if (pcache < tgt) {
        pcache = poll_ge_wg(&pflag[w - 1], tgt, pcache);
        asm volatile("" ::: "memory");
      }
    }
    if (w < 5 && s4 >= 36) {
      const int tgt = s4 - 32;
      if (ccache < tgt) {
        ccache = poll_ge_wg(&cflag[w + 1], tgt, ccache);
        asm volatile("" ::: "memory");
      }
    }

    if (s4 >= 4 && s4 < 1012) {
      step(s4 + 0, false); step(s4 + 1, false); step(s4 + 2, false); step(s4 + 3, false);
    } else {
      step(s4 + 0, true);  step(s4 + 1, true);  step(s4 + 2, true);  step(s4 + 3, true);
    }

    // ---- relaxed flag posts (DS pipe in-order per wave orders data before flag) ----
    if (lane == 0) {
      asm volatile("" ::: "memory");
      if (w < 5)
        __hip_atomic_store(&pflag[w], s4, __ATOMIC_RELAXED, __HIP_MEMORY_SCOPE_WORKGROUP);
      if (w > 0 && s4 + 3 < TT)
        __hip_atomic_store(&cflag[w], s4 + 4, __ATOMIC_RELAXED, __HIP_MEMORY_SCOPE_WORKGROUP);
    }
  }

  // ---- epilogue: unblock any remaining pollers ----
  if (lane == 0) {
    asm volatile("" ::: "memory");
    if (w < 5) __hip_atomic_store(&pflag[w], BIGF, __ATOMIC_RELAXED, __HIP_MEMORY_SCOPE_WORKGROUP);
    if (w > 0) __hip_atomic_store(&cflag[w], BIGF, __ATOMIC_RELAXED, __HIP_MEMORY_SCOPE_WORKGROUP);
    if (is_feeder && seg > 0)
      __hip_atomic_store(&cons[hop_in], BIGF, __ATOMIC_RELAXED, __HIP_MEMORY_SCOPE_AGENT);
  }
}

// ---------------- head: lin1+relu, lin2+relu, mu, softplus(sigma) ----------------
__global__ void k_head(const float* __restrict__ hfin,
                       const float* __restrict__ w1, const float* __restrict__ b1,
                       const float* __restrict__ w2, const float* __restrict__ b2,
                       const float* __restrict__ wm, const float* __restrict__ bm,
                       const float* __restrict__ wsg, const float* __restrict__ bsg,
                       float* __restrict__ out)
{
  const int tid = threadIdx.x;
  __shared__ float s1[144], s2[144], sm[144], ss[144];
  __shared__ float v1[12], v2[12], vm[12], vs[12];
  if (tid < 144) { s1[tid] = w1[tid]; s2[tid] = w2[tid]; sm[tid] = wm[tid]; ss[tid] = wsg[tid]; }
  if (tid < 12)  { v1[tid] = b1[tid]; v2[tid] = b2[tid]; vm[tid] = bm[tid]; vs[tid] = bsg[tid]; }
  __syncthreads();
  const int r = blockIdx.x * 256 + tid;   // 0..7679 = b*120 + l
  const int b = r / 120, l = r - b * 120;
  float h[12];
#pragma unroll
  for (int k = 0; k < 12; ++k) h[k] = hfin[l * 768 + b * 12 + k];
  float u1[12];
#pragma unroll
  for (int u = 0; u < 12; ++u) {
    float a = v1[u];
#pragma unroll
    for (int k = 0; k < 12; ++k) a += s1[u * 12 + k] * h[k];
    u1[u] = fmaxf(a, 0.f);
  }
  float u2[12];
#pragma unroll
  for (int u = 0; u < 12; ++u) {
    float a = v2[u];
#pragma unroll
    for (int k = 0; k < 12; ++k) a += s2[u * 12 + k] * u1[k];
    u2[u] = fmaxf(a, 0.f);
  }
  const size_t base = (size_t)r * 12;
#pragma unroll
  for (int u = 0; u < 12; ++u) out[base + u] = u2[u];
#pragma unroll
  for (int u = 0; u < 12; ++u) {
    float a = vm[u];
#pragma unroll
    for (int k = 0; k < 12; ++k) a += sm[u * 12 + k] * u2[k];
    out[92160 + base + u] = a;
  }
#pragma unroll
  for (int u = 0; u < 12; ++u) {
    float a = vs[u];
#pragma unroll
    for (int k = 0; k < 12; ++k) a += ss[u * 12 + k] * u2[k];
    out[184320 + base + u] = fmaxf(a, 0.f) + log1pf(expf(-fabsf(a)));
  }
}

// ---------------- launcher ----------------
extern "C" void kernel_launch(void* const* d_in, const int* in_sizes, int n_in,
                              void* d_out, int out_size, void* d_ws, size_t ws_size,
                              hipStream_t stream)
{
  const float* x   = (const float*)d_in[0];
  const float* c1w = (const float*)d_in[1];
  const float* c1b = (const float*)d_in[2];
  const float* g1  = (const float*)d_in[3];
  const float* be1 = (const float*)d_in[4];
  const float* c2w = (const float*)d_in[5];
  const float* c2b = (const float*)d_in[6];
  const float* g2  = (const float*)d_in[7];
  const float* be2 = (const float*)d_in[8];
  const float* aw  = (const float*)d_in[9];
  const float* ab  = (const float*)d_in[10];
  const float* wih = (const float*)d_in[11];
  const float* whh = (const float*)d_in[12];
  const float* bih = (const float*)d_in[13];
  const float* bhh = (const float*)d_in[14];
  const float* l1w = (const float*)d_in[15];
  const float* l1b = (const float*)d_in[16];
  const float* l2w = (const float*)d_in[17];
  const float* l2b = (const float*)d_in[18];
  const float* muw = (const float*)d_in[19];
  const float* mub = (const float*)d_in[20];
  const float* sgw = (const float*)d_in[21];
  const float* sgb = (const float*)d_in[22];

  float* ws    = (float*)d_ws;
  float* stat1 = ws;                    // 12
  float* stat2 = ws + 12;               // 12
  float* aff1  = ws + 24;               // 12
  float* aff2  = ws + 36;               // 12
  int*   prog  = (int*)(ws + 64);       // 192 used
  int*   cons  = (int*)(ws + 304);      // 192 used
  float* y1    = ws + 576;              // 64*6*1020
  float* y2    = y1 + 391680;           // 64*6*1016
  float* seq0  = y2 + 390144;           // 1016*768
  float* ring  = seq0 + 780288;         // 192 hops * 8 batches * 192 floats
  float* hfin  = ring + (size_t)192 * RB * 192;   // 120*768

  hipMemsetAsync(d_ws, 0, 576 * sizeof(float), stream);  // zero stats + flags

  k_conv<<<384, 256, 0, stream>>>(x, c1w, c1b, nullptr, y1, stat1, 1024, 1020, 0);
  k_finalize<<<1, 64, 0, stream>>>(stat1, g1, be1, aff1, 1.f / 65280.f);
  k_conv<<<384, 256, 0, stream>>>(y1, c2w, c2b, aff1, y2, stat2, 1020, 1016, 1);
  k_finalize<<<1, 64, 0, stream>>>(stat2, g2, be2, aff2, 1.f / 65024.f);
  k_attn<<<1016, 768, 0, stream>>>(y2, aff2, aw, ab, seq0);
  k_lstm<<<256, TPB, 0, stream>>>(wih, whh, bih, bhh, seq0, ring, prog, cons, hfin);
  k_head<<<30, 256, 0, stream>>>(hfin, l1w, l1b, l2w, l2b, muw, mub, sgw, sgb, (float*)d_out);
}

// Round 7
// 816.822 us; speedup vs baseline: 2.0813x; 1.0030x over previous
//
#include <hip/hip_runtime.h>
#include <math.h>

// ---------------- problem constants ----------------
#define NLAY 120         // LSTM layers
#define TT   1016        // LSTM time steps (1024 - 4 - 4)
#define NB   64          // batches of 16 steps (64*16 = 1024 >= TT+4)
#define RB   8           // L3 ring depth in batches (power of 2)
#define IRS  32          // intra-block inter-wave LDS ring slots (power of 2)
#define TPB  384         // 6 waves x 64 lanes; wave = 5 layers x 12 hidden (lanes 60-63 idle)
#define BIGF (1 << 20)

typedef float v2f __attribute__((ext_vector_type(2)));

__device__ __forceinline__ float fast_rcp(float x) { return __builtin_amdgcn_rcpf(x); }
__device__ __forceinline__ float fast_sig(float x) { return fast_rcp(1.f + __expf(-x)); }
__device__ __forceinline__ float fast_tanh(float x) { return 1.f - 2.f * fast_rcp(1.f + __expf(2.f * x)); }

// agent-scope relaxed poll (global flags); s_sleep on miss; watchdog fails loud, never hangs
__device__ __forceinline__ int poll_ge_ag(const int* p, int tgt, int cur) {
  long g = 0;
  while (cur < tgt) {
    cur = __hip_atomic_load(p, __ATOMIC_RELAXED, __HIP_MEMORY_SCOPE_AGENT);
    if (cur >= tgt) break;
    __builtin_amdgcn_s_sleep(1);
    if (++g > 400000L) break;
  }
  return cur;
}
// workgroup-scope relaxed poll on an LDS flag (ds_read spin)
__device__ __forceinline__ int poll_ge_wg(const int* p, int tgt, int cur) {
  long g = 0;
  while (cur < tgt) {
    cur = __hip_atomic_load(p, __ATOMIC_RELAXED, __HIP_MEMORY_SCOPE_WORKGROUP);
    if (cur >= tgt) break;
    __builtin_amdgcn_s_sleep(1);
    if (++g > 400000L) break;
  }
  return cur;
}

// ---------------- conv1d(6->6,K=5,valid) + bias, accumulate BN stats ----------------
__global__ void k_conv(const float* __restrict__ xin, const float* __restrict__ cw,
                       const float* __restrict__ cb, const float* __restrict__ aff,
                       float* __restrict__ yout, float* __restrict__ stat,
                       int Tin, int Tout, int use_aff)
{
  const int bx = blockIdx.x;            // 0..383 : b*6+co
  const int b = bx / 6, co = bx - b * 6;
  const int tid = threadIdx.x;          // 256
  __shared__ float wsh[30];
  __shared__ float ssh[6], shsh[6];
  if (tid < 30) wsh[tid] = cw[co * 30 + tid];
  if (tid < 6) {
    ssh[tid]  = use_aff ? aff[tid] : 1.f;
    shsh[tid] = use_aff ? aff[6 + tid] : 0.f;
  }
  __syncthreads();
  const float bias = cb[co];
  float lsum = 0.f, lsq = 0.f;
  for (int t = tid; t < Tout; t += 256) {
    float acc = bias;
#pragma unroll
    for (int ci = 0; ci < 6; ++ci) {
      const float* xr = xin + ((size_t)b * 6 + ci) * Tin + t;
      const float s = ssh[ci], sh = shsh[ci];
#pragma unroll
      for (int k = 0; k < 5; ++k) {
        float v = xr[k];
        if (use_aff) v = fmaxf(fmaf(s, v, sh), 0.f);
        acc += wsh[ci * 5 + k] * v;
      }
    }
    yout[((size_t)b * 6 + co) * Tout + t] = acc;
    lsum += acc; lsq += acc * acc;
  }
  __shared__ float rs[256], rq[256];
  rs[tid] = lsum; rq[tid] = lsq;
  __syncthreads();
  for (int s = 128; s > 0; s >>= 1) {
    if (tid < s) { rs[tid] += rs[tid + s]; rq[tid] += rq[tid + s]; }
    __syncthreads();
  }
  if (tid == 0) { atomicAdd(&stat[co], rs[0]); atomicAdd(&stat[6 + co], rq[0]); }
}

// ---------------- finalize BN: stats -> per-channel scale/shift ----------------
__global__ void k_finalize(const float* __restrict__ stat,
                           const float* __restrict__ gamma, const float* __restrict__ beta,
                           float* __restrict__ aff, float invN)
{
  const int c = threadIdx.x;
  if (c < 6) {
    float mean = stat[c] * invN;
    float var  = stat[6 + c] * invN - mean * mean;
    float sc   = gamma[c] * rsqrtf(var + 1e-5f);
    aff[c]     = sc;
    aff[6 + c] = fmaf(-mean, sc, beta[c]);
  }
}

// ---------------- BN2+ReLU + attn projection (6->12) + ReLU; write seq0[t][b*12+j] ----------------
__global__ void k_attn(const float* __restrict__ y2, const float* __restrict__ aff2,
                       const float* __restrict__ aw, const float* __restrict__ ab,
                       float* __restrict__ seq0)
{
  const int t = blockIdx.x;             // 0..1015
  const int tid = threadIdx.x;          // 0..767
  __shared__ float zb[6 * 64];
  if (tid < 384) {
    const int c = tid >> 6, bb = tid & 63;
    float v = y2[((size_t)bb * 6 + c) * TT + t];
    zb[c * 64 + bb] = fmaxf(fmaf(aff2[c], v, aff2[6 + c]), 0.f);
  }
  __syncthreads();
  const int b = tid / 12, j = tid - b * 12;
  float acc = ab[j];
#pragma unroll
  for (int c = 0; c < 6; ++c) acc += aw[j * 6 + c] * zb[c * 64 + b];
  seq0[(size_t)t * 768 + tid] = fmaxf(acc, 0.f);
}

// ---------------- 120-layer LSTM: free-running waves, relaxed LDS flag protocol ----------------
// grid = 256 blocks: bid = chain*4 + seg. Wave w = 5-layer stage; lane (p,j) = layer w*5+p.
// Diagonal: at step s, group p computes t = s - p.
// ROUND-7 CHANGE (single variable vs round 6): __launch_bounds__(TPB, 1) instead of (TPB, 2).
// The grid is exactly 256 blocks = 1 block/CU, but min-blocks=2 made the compiler budget for
// 3 waves/SIMD -> 160 total VGPRs/wave, split 92 arch + 68 ACCUM (rocprof arithmetic: 92+68
// = 160 exactly). v_pk_fma cannot source AGPRs, so every step paid ~70-80 v_accvgpr_read
// moves to shuttle weights accum->arch — the hidden VALU tax (measured ~190 instr/step/wave
// vs ~110 core math). min-blocks=1 -> 2 waves/SIMD -> 256-VGPR budget -> weights live in
// arch VGPRs, accvgpr traffic gone. (r5's (640,3) -> 64-reg budget -> 24GB scratch writes
// was the same bug at a pathological extreme.)
__global__ __launch_bounds__(TPB, 1) void k_lstm(
    const float* __restrict__ wih, const float* __restrict__ whh,
    const float* __restrict__ bih, const float* __restrict__ bhh,
    const float* __restrict__ seq0, float* __restrict__ ring,
    int* __restrict__ prog, int* __restrict__ cons,
    float* __restrict__ hfin)
{
  const int bid  = blockIdx.x;         // 0..255
  const int c    = bid >> 2;           // chain = batch element
  const int seg  = bid & 3;
  const int tid  = threadIdx.x;
  const int w    = tid >> 6;           // wave 0..5
  const int lane = tid & 63;
  const int p    = lane / 12;          // 0..5 (5 = pad group)
  const int j    = lane - p * 12;
  const bool act = (p < 5);
  const int pc   = act ? p : 0;        // clamped for safe addressing
  const int l    = seg * 30 + w * 5 + pc;

  // ---- LDS ----
  __shared__ __align__(16) float hloc[6][2][64];        // per-wave double buffer (+pad slots 60..63)
  __shared__ __align__(16) float iring[5][IRS][12];     // wave w -> w+1
  __shared__ __align__(16) float xring[2][16][12];      // feeder input (wave 0 private)
  __shared__ __align__(16) float oring[16][12];         // tailer staging (wave 5 private)
  __shared__ int pflag[6];                              // produced-count, posted by wave w (w<5)
  __shared__ int cflag[8];                              // consumed-count, posted by wave w (w>0)
  float* xrf = &xring[0][0][0];

  if (tid < 6) pflag[tid] = 0;
  if (tid < 8) cflag[tid] = 0;
  hloc[w][0][lane] = 0.f; hloc[w][1][lane] = 0.f;
  __syncthreads();   // ONE barrier, before the main loop only

  // ---- gate weights as (i,f),(g,o) float2 pairs -> v_pk_fma_f32 ----
  v2f wx_if[12] = {}, wx_go[12] = {}, wh_if[12] = {}, wh_go[12] = {};
  v2f b_if = (v2f){0.f, 0.f}, b_go = (v2f){0.f, 0.f};
  if (act) {
    const float* wi = wih + l * 576;
    const float* wh = whh + l * 576;
#pragma unroll
    for (int k = 0; k < 12; ++k) {
      wx_if[k] = (v2f){ wi[(j     ) * 12 + k], wi[(j + 12) * 12 + k] };
      wx_go[k] = (v2f){ wi[(j + 24) * 12 + k], wi[(j + 36) * 12 + k] };
      wh_if[k] = (v2f){ wh[(j     ) * 12 + k], wh[(j + 12) * 12 + k] };
      wh_go[k] = (v2f){ wh[(j + 24) * 12 + k], wh[(j + 36) * 12 + k] };
    }
    const float* ba = bih + l * 48;
    const float* bb = bhh + l * 48;
    b_if = (v2f){ ba[j]      + bb[j],      ba[j + 12] + bb[j + 12] };
    b_go = (v2f){ ba[j + 24] + bb[j + 24], ba[j + 36] + bb[j + 36] };
  }
  // PIN: asm def breaks load-rematerialization and forces ARCH-VGPR residency.
#pragma unroll
  for (int k = 0; k < 12; ++k) {
    asm volatile("" : "+v"(wx_if[k]), "+v"(wx_go[k]));
    asm volatile("" : "+v"(wh_if[k]), "+v"(wh_go[k]));
  }
  asm volatile("" : "+v"(b_if), "+v"(b_go));

  // ---- feeder / tailer plumbing ----
  const int hop_in  = c * 3 + seg - 1;                 // valid if seg>0
  const int hop_out = c * 3 + seg;                     // valid if seg<3
  const float* rin  = ring + (size_t)((seg > 0) ? hop_in : 0) * (RB * 192);
  float*       rout = ring + (size_t)((seg < 3) ? hop_out : 0) * (RB * 192);
  const bool is_feeder = (w == 0);
  const bool is_tailer = (w == 5) && (seg < 3);

  const int f0 = lane, f1 = lane + 64, f2 = lane + 128;   // cooperative 192-float copy
  const int s0o0 = (f0 / 12) * 768 + (f0 % 12);           // seq0 gather offsets
  const int s0o1 = (f1 / 12) * 768 + (f1 % 12);
  const int s0o2 = (f2 / 12) * 768 + (f2 % 12);

  auto ld_batch = [&](int m, float* d) {
    if (seg == 0) {
      const float* b = seq0 + (size_t)m * 16 * 768 + c * 12;
      d[0] = b[s0o0]; d[1] = b[s0o1]; d[2] = b[s0o2];
    } else {
      const float* b = rin + (m & (RB - 1)) * 192;
      d[0] = __hip_atomic_load(b + f0, __ATOMIC_RELAXED, __HIP_MEMORY_SCOPE_AGENT);
      d[1] = __hip_atomic_load(b + f1, __ATOMIC_RELAXED, __HIP_MEMORY_SCOPE_AGENT);
      d[2] = __hip_atomic_load(b + f2, __ATOMIC_RELAXED, __HIP_MEMORY_SCOPE_AGENT);
    }
  };

  float pend[3] = {0.f, 0.f, 0.f};
  int kp = 0, kcons = 0;
  if (is_feeder) {
    if (seg > 0) kp = poll_ge_ag(&prog[hop_in], 2, 0);
    float cur[3];
    ld_batch(0, cur);
    ld_batch(1, pend);
    xrf[f0] = cur[0]; xrf[f1] = cur[1]; xrf[f2] = cur[2];   // batch 0 -> buffer 0
  }

  float cst = 0.f;
  int pcache = 0, ccache = 0;

  // ---- one LSTM step; `guard` constant-folds per call site ----
  auto step = [&](int s, bool guard) __attribute__((always_inline)) {
    const int t  = s - pc;
    const int rb = (s & 1) ^ 1, wb = s & 1;

    const float* ax;
    if (p == 0) ax = (w == 0) ? (xrf + ((s >> 4) & 1) * 192 + (s & 15) * 12)
                              : (&iring[w - 1][s & (IRS - 1)][0]);
    else        ax = &hloc[w][rb][(pc == 0 ? 0 : pc - 1) * 12];
    const float* ah = &hloc[w][rb][pc * 12];

    float4 xA = ((const float4*)ax)[0], xB = ((const float4*)ax)[1], xC = ((const float4*)ax)[2];
    float4 hA = ((const float4*)ah)[0], hB = ((const float4*)ah)[1], hC = ((const float4*)ah)[2];
    float xv[12] = {xA.x,xA.y,xA.z,xA.w, xB.x,xB.y,xB.z,xB.w, xC.x,xC.y,xC.z,xC.w};
    float hv[12] = {hA.x,hA.y,hA.z,hA.w, hB.x,hB.y,hB.z,hB.w, hC.x,hC.y,hC.z,hC.w};

    v2f axif = (v2f){0.f,0.f}, axgo = (v2f){0.f,0.f};
    v2f ahif = b_if, ahgo = b_go;
#pragma unroll
    for (int k = 0; k < 12; ++k) {
      v2f xx = { xv[k], xv[k] };
      axif = __builtin_elementwise_fma(wx_if[k], xx, axif);
      axgo = __builtin_elementwise_fma(wx_go[k], xx, axgo);
    }
#pragma unroll
    for (int k = 0; k < 12; ++k) {
      v2f hh = { hv[k], hv[k] };
      ahif = __builtin_elementwise_fma(wh_if[k], hh, ahif);
      ahgo = __builtin_elementwise_fma(wh_go[k], hh, ahgo);
    }
    v2f aif = axif + ahif, ago = axgo + ahgo;
    float ig = fast_sig(aif.x);
    float fg = fast_sig(aif.y);
    float gg = fast_tanh(ago.x);
    float og = fast_sig(ago.y);

    if (!guard) {
      // steady region: all t valid; idle lanes write their pad slot
      cst = fg * cst + ig * gg;
      float hn = og * fast_tanh(cst);
      hloc[w][wb][p * 12 + j] = hn;
      if (p == 4) {
        if (w < 5) iring[w][t & (IRS - 1)][j] = hn;
        else if (seg < 3) oring[t & 15][j] = hn;
      }
    } else {
      const bool run = act && (t >= 0) && (t < TT);
      if (run) {
        cst = fg * cst + ig * gg;
        float hn = og * fast_tanh(cst);
        hloc[w][wb][p * 12 + j] = hn;
        if (p == 4) {
          if (w < 5) iring[w][t & (IRS - 1)][j] = hn;
          else if (seg < 3) oring[t & 15][j] = hn;
        }
        if (t == TT - 1) hfin[l * 768 + c * 12 + j] = hn;
      }
    }

    // tailer: flush a completed 16-step batch to the L3 ring (wave-uniform branch)
    if (is_tailer) {
      const int t4 = s - 4;
      if (t4 >= 0 && t4 < TT && (((t4 & 15) == 15) || t4 == TT - 1)) {
        const int m4 = t4 >> 4;
        if (kcons < m4 - (RB - 1) + 1)
          kcons = poll_ge_ag(&cons[hop_out], m4 - RB + 1, kcons);
        const float* orf = &oring[0][0];
        float o0 = orf[f0], o1 = orf[f1], o2 = orf[f2];
        float* d = rout + (m4 & (RB - 1)) * 192;
        __hip_atomic_store(d + f0, o0, __ATOMIC_RELAXED, __HIP_MEMORY_SCOPE_AGENT);
        __hip_atomic_store(d + f1, o1, __ATOMIC_RELAXED, __HIP_MEMORY_SCOPE_AGENT);
        __hip_atomic_store(d + f2, o2, __ATOMIC_RELAXED, __HIP_MEMORY_SCOPE_AGENT);
        if (lane == 0)   // RELEASE: drains this wave's 3 stores; other waves keep running
          __hip_atomic_store(&prog[hop_out], m4 + 1, __ATOMIC_RELEASE, __HIP_MEMORY_SCOPE_AGENT);
      }
    }
  };

  for (int s4 = 0; s4 < 1024; s4 += 4) {
    // ---- batch boundary: feeder publishes batch m+1, starts loads for m+2 ----
    if (is_feeder && (s4 & 15) == 0) {
      const int m = s4 >> 4;
      if (m + 1 < NB) {
        float* xd = xrf + ((m + 1) & 1) * 192;
        xd[f0] = pend[0]; xd[f1] = pend[1]; xd[f2] = pend[2];
      }
      if (m + 2 < NB) {
        if (seg > 0 && kp < m + 3) kp = poll_ge_ag(&prog[hop_in], m + 3, kp);
        ld_batch(m + 2, pend);     // stays in flight for the next 16 steps (no drains now)
      }
      if (seg > 0 && lane == 0)
        __hip_atomic_store(&cons[hop_in], m, __ATOMIC_RELAXED, __HIP_MEMORY_SCOPE_AGENT);
    }

    // ---- relaxed LDS flag checks, once per 4 steps ----
    if (w > 0 && s4 < TT) {
      const int tgt = (s4 + 4 < TT) ? (s4 + 4) : TT;
      if (pcache < tgt) {
        pcache = poll_ge_wg(&pflag[w - 1], tgt, pcache);
        asm volatile("" ::: "memory");
      }
    }
    if (w < 5 && s4 >= 36) {
      const int tgt = s4 - 32;
      if (ccache < tgt) {
        ccache = poll_ge_wg(&cflag[w + 1], tgt, ccache);
        asm volatile("" ::: "memory");
      }
    }

    if (s4 >= 4 && s4 < 1012) {
      step(s4 + 0, false); step(s4 + 1, false); step(s4 + 2, false); step(s4 + 3, false);
    } else {
      step(s4 + 0, true);  step(s4 + 1, true);  step(s4 + 2, true);  step(s4 + 3, true);
    }

    // ---- relaxed flag posts (DS pipe in-order per wave orders data before flag) ----
    if (lane == 0) {
      asm volatile("" ::: "memory");
      if (w < 5)
        __hip_atomic_store(&pflag[w], s4, __ATOMIC_RELAXED, __HIP_MEMORY_SCOPE_WORKGROUP);
      if (w > 0 && s4 + 3 < TT)
        __hip_atomic_store(&cflag[w], s4 + 4, __ATOMIC_RELAXED, __HIP_MEMORY_SCOPE_WORKGROUP);
    }
  }

  // ---- epilogue: unblock any remaining pollers ----
  if (lane == 0) {
    asm volatile("" ::: "memory");
    if (w < 5) __hip_atomic_store(&pflag[w], BIGF, __ATOMIC_RELAXED, __HIP_MEMORY_SCOPE_WORKGROUP);
    if (w > 0) __hip_atomic_store(&cflag[w], BIGF, __ATOMIC_RELAXED, __HIP_MEMORY_SCOPE_WORKGROUP);
    if (is_feeder && seg > 0)
      __hip_atomic_store(&cons[hop_in], BIGF, __ATOMIC_RELAXED, __HIP_MEMORY_SCOPE_AGENT);
  }
}

// ---------------- head: lin1+relu, lin2+relu, mu, softplus(sigma) ----------------
__global__ void k_head(const float* __restrict__ hfin,
                       const float* __restrict__ w1, const float* __restrict__ b1,
                       const float* __restrict__ w2, const float* __restrict__ b2,
                       const float* __restrict__ wm, const float* __restrict__ bm,
                       const float* __restrict__ wsg, const float* __restrict__ bsg,
                       float* __restrict__ out)
{
  const int tid = threadIdx.x;
  __shared__ float s1[144], s2[144], sm[144], ss[144];
  __shared__ float v1[12], v2[12], vm[12], vs[12];
  if (tid < 144) { s1[tid] = w1[tid]; s2[tid] = w2[tid]; sm[tid] = wm[tid]; ss[tid] = wsg[tid]; }
  if (tid < 12)  { v1[tid] = b1[tid]; v2[tid] = b2[tid]; vm[tid] = bm[tid]; vs[tid] = bsg[tid]; }
  __syncthreads();
  const int r = blockIdx.x * 256 + tid;   // 0..7679 = b*120 + l
  const int b = r / 120, l = r - b * 120;
  float h[12];
#pragma unroll
  for (int k = 0; k < 12; ++k) h[k] = hfin[l * 768 + b * 12 + k];
  float u1[12];
#pragma unroll
  for (int u = 0; u < 12; ++u) {
    float a = v1[u];
#pragma unroll
    for (int k = 0; k < 12; ++k) a += s1[u * 12 + k] * h[k];
    u1[u] = fmaxf(a, 0.f);
  }
  float u2[12];
#pragma unroll
  for (int u = 0; u < 12; ++u) {
    float a = v2[u];
#pragma unroll
    for (int k = 0; k < 12; ++k) a += s2[u * 12 + k] * u1[k];
    u2[u] = fmaxf(a, 0.f);
  }
  const size_t base = (size_t)r * 12;
#pragma unroll
  for (int u = 0; u < 12; ++u) out[base + u] = u2[u];
#pragma unroll
  for (int u = 0; u < 12; ++u) {
    float a = vm[u];
#pragma unroll
    for (int k = 0; k < 12; ++k) a += sm[u * 12 + k] * u2[k];
    out[92160 + base + u] = a;
  }
#pragma unroll
  for (int u = 0; u < 12; ++u) {
    float a = vs[u];
#pragma unroll
    for (int k = 0; k < 12; ++k) a += ss[u * 12 + k] * u2[k];
    out[184320 + base + u] = fmaxf(a, 0.f) + log1pf(expf(-fabsf(a)));
  }
}

// ---------------- launcher ----------------
extern "C" void kernel_launch(void* const* d_in, const int* in_sizes, int n_in,
                              void* d_out, int out_size, void* d_ws, size_t ws_size,
                              hipStream_t stream)
{
  const float* x   = (const float*)d_in[0];
  const float* c1w = (const float*)d_in[1];
  const float* c1b = (const float*)d_in[2];
  const float* g1  = (const float*)d_in[3];
  const float* be1 = (const float*)d_in[4];
  const float* c2w = (const float*)d_in[5];
  const float* c2b = (const float*)d_in[6];
  const float* g2  = (const float*)d_in[7];
  const float* be2 = (const float*)d_in[8];
  const float* aw  = (const float*)d_in[9];
  const float* ab  = (const float*)d_in[10];
  const float* wih = (const float*)d_in[11];
  const float* whh = (const float*)d_in[12];
  const float* bih = (const float*)d_in[13];
  const float* bhh = (const float*)d_in[14];
  const float* l1w = (const float*)d_in[15];
  const float* l1b = (const float*)d_in[16];
  const float* l2w = (const float*)d_in[17];
  const float* l2b = (const float*)d_in[18];
  const float* muw = (const float*)d_in[19];
  const float* mub = (const float*)d_in[20];
  const float* sgw = (const float*)d_in[21];
  const float* sgb = (const float*)d_in[22];

  float* ws    = (float*)d_ws;
  float* stat1 = ws;                    // 12
  float* stat2 = ws + 12;               // 12
  float* aff1  = ws + 24;               // 12
  float* aff2  = ws + 36;               // 12
  int*   prog  = (int*)(ws + 64);       // 192 used
  int*   cons  = (int*)(ws + 304);      // 192 used
  float* y1    = ws + 576;              // 64*6*1020
  float* y2    = y1 + 391680;           // 64*6*1016
  float* seq0  = y2 + 390144;           // 1016*768
  float* ring  = seq0 + 780288;         // 192 hops * 8 batches * 192 floats
  float* hfin  = ring + (size_t)192 * RB * 192;   // 120*768

  hipMemsetAsync(d_ws, 0, 576 * sizeof(float), stream);  // zero stats + flags

  k_conv<<<384, 256, 0, stream>>>(x, c1w, c1b, nullptr, y1, stat1, 1024, 1020, 0);
  k_finalize<<<1, 64, 0, stream>>>(stat1, g1, be1, aff1, 1.f / 65280.f);
  k_conv<<<384, 256, 0, stream>>>(y1, c2w, c2b, aff1, y2, stat2, 1020, 1016, 1);
  k_finalize<<<1, 64, 0, stream>>>(stat2, g2, be2, aff2, 1.f / 65024.f);
  k_attn<<<1016, 768, 0, stream>>>(y2, aff2, aw, ab, seq0);
  k_lstm<<<256, TPB, 0, stream>>>(wih, whh, bih, bhh, seq0, ring, prog, cons, hfin);
  k_head<<<30, 256, 0, stream>>>(hfin, l1w, l1b, l2w, l2b, muw, mub, sgw, sgb, (float*)d_out);
}